// Round 9
// baseline (735.007 us; speedup 1.0000x reference)
//
#include <hip/hip_runtime.h>
#include <math.h>

#define BB   64
#define LL   256
#define EE   512
#define DD   512
#define BL   (BB * LL)      // 16384
#define BL2  (2 * BL)       // 32768 (prem rows then hypo rows)
#define MAX_DIST 11

typedef __attribute__((ext_vector_type(8))) short bf16x8;
typedef __attribute__((ext_vector_type(8))) unsigned short u16x8;
typedef __attribute__((ext_vector_type(4))) float f32x4;

__device__ __forceinline__ float bf2f(unsigned short u) {
    union { unsigned int u; float f; } v; v.u = ((unsigned int)u) << 16; return v.f;
}
__device__ __forceinline__ unsigned short f2bf(float f) {
    union { float f; unsigned int u; } v; v.f = f;
    unsigned int r = v.u + 0x7FFF + ((v.u >> 16) & 1);   // RNE
    return (unsigned short)(r >> 16);
}

#define GLOAD16(g, l)                                                          \
    __builtin_amdgcn_global_load_lds(                                          \
        (const __attribute__((address_space(1))) void*)(g),                    \
        (__attribute__((address_space(3))) void*)(l), 16, 0, 0)

// ---------------------------------------------------------------------------
// bf16 MFMA GEMM, BK=64, tile MTx256 (MT = 128: 4 waves, MT = 256: 8 waves;
// wave tile 64x128 in both).
// MODE 0: C = act([A0|A1]*B^T + bias), bf16 out, coalesced LDS epilogue.
// MODE 1: fused row-softmax epilogue (N==256, gridDim.y==1).
// MODE 2: masked row-reduce epilogue -> atomicAdd rout [64,1024], no C.
// MODE 3: MODE 0 + transposed store tout[b][col][row].
// shareAB (runtime, requires gridDim.x==1 && M==256): A rows == B rows ->
//   skip A staging, read A fragments from Bs (self-scores QQ^T).
// B batch index is (b ^ bxor).
// MT=256 halves B-staging traffic for batched attention GEMMs (B rows
// staged once per batch instead of twice).
// ---------------------------------------------------------------------------
template <int MODE, int MT>
__global__ __launch_bounds__(MT * 2, 2) void bgemm_kernel(
    const unsigned short* __restrict__ A0, int K0, int lda0, long long bsA0,
    const unsigned short* __restrict__ A1, int lda1, long long bsA1,
    const unsigned short* __restrict__ B, int ldb, long long bsB, int bxor,
    const float* __restrict__ bias,
    void* __restrict__ Cv, int ldc, long long bsC,
    int K, int relu, int shareAB,
    const float* __restrict__ smask, const float* __restrict__ distW,
    int diag, int maskXor,
    float* __restrict__ rout, const float* __restrict__ rmask,
    unsigned short* __restrict__ tout, long long tbs)
{
    constexpr int BN   = 256;
    constexpr int NI   = 8;
    constexpr int NT   = MT * 2;            // threads
    constexpr int NW   = MT / 32;           // waves
    __shared__ unsigned short smem[(MT + 256) * 64];
    unsigned short* As = smem;
    unsigned short* Bs = smem + MT * 64;

    const int tid  = threadIdx.x;
    const int wave = tid >> 6;
    const int lane = tid & 63;
    const int quad = lane >> 4;
    const int l15  = lane & 15;
    const int wm   = (wave >> 1) * 64;
    const int wn   = (wave & 1) * 128;
    const int row0 = blockIdx.x * MT;
    const int col0 = blockIdx.y * BN;
    const int b    = blockIdx.z;

    const unsigned short* A0b = A0 + (long long)b * bsA0;
    const unsigned short* A1b = A1 ? (A1 + (long long)b * bsA1) : nullptr;
    const unsigned short* Bb  = B + (long long)(b ^ bxor) * bsB;

    f32x4 acc[4][NI];
#pragma unroll
    for (int i = 0; i < 4; ++i)
#pragma unroll
        for (int j = 0; j < NI; ++j)
            acc[i][j] = (f32x4){0.f, 0.f, 0.f, 0.f};

    for (int kk = 0; kk < K; kk += 64) {
        if (!shareAB) {
            const unsigned short* Ap; int lda, kloc;
            if (kk < K0) { Ap = A0b; lda = lda0; kloc = kk; }
            else         { Ap = A1b; lda = lda1; kloc = kk - K0; }
#pragma unroll
            for (int it = 0; it < 4; ++it) {
                const int c   = it * NT + tid;
                const int row = c >> 3;
                const int kch = (c & 7) ^ (row & 7);
                GLOAD16(Ap + (long long)(row0 + row) * lda + kloc + kch * 8,
                        (char*)As + c * 16);
            }
        }
#pragma unroll
        for (int it = 0; it < 2048 / NT; ++it) {
            const int c   = it * NT + tid;
            const int row = c >> 3;
            const int kch = (c & 7) ^ (row & 7);
            GLOAD16(Bb + (long long)(col0 + row) * ldb + kk + kch * 8,
                    (char*)Bs + c * 16);
        }
        __syncthreads();

        const unsigned short* Af = shareAB ? Bs : As;
#pragma unroll
        for (int s = 0; s < 2; ++s) {
            bf16x8 fa[4], fb[NI];
#pragma unroll
            for (int mi = 0; mi < 4; ++mi) {
                const int r = wm + mi * 16 + l15;
                const int slot = (s * 4 + quad) ^ (r & 7);
                fa[mi] = *(const bf16x8*)&Af[(r * 8 + slot) * 8];
            }
#pragma unroll
            for (int ni = 0; ni < NI; ++ni) {
                const int r = wn + ni * 16 + l15;
                const int slot = (s * 4 + quad) ^ (r & 7);
                fb[ni] = *(const bf16x8*)&Bs[(r * 8 + slot) * 8];
            }
#pragma unroll
            for (int mi = 0; mi < 4; ++mi)
#pragma unroll
                for (int ni = 0; ni < NI; ++ni)
                    acc[mi][ni] = __builtin_amdgcn_mfma_f32_16x16x32_bf16(
                        fa[mi], fb[ni], acc[mi][ni], 0, 0, 0);
        }
        __syncthreads();
    }

    if constexpr (MODE == 2) {
        float bv[NI];
#pragma unroll
        for (int ni = 0; ni < NI; ++ni)
            bv[ni] = bias[col0 + wn + ni * 16 + l15];
        float mrow[4][4];
#pragma unroll
        for (int mi = 0; mi < 4; ++mi)
#pragma unroll
            for (int r = 0; r < 4; ++r)
                mrow[mi][r] = rmask[row0 + wm + mi * 16 + quad * 4 + r];
        float t[NI];
#pragma unroll
        for (int ni = 0; ni < NI; ++ni) t[ni] = 0.f;
#pragma unroll
        for (int mi = 0; mi < 4; ++mi)
#pragma unroll
            for (int ni = 0; ni < NI; ++ni)
#pragma unroll
                for (int r = 0; r < 4; ++r) {
                    float x = fmaxf(acc[mi][ni][r] + bv[ni], 0.f);
                    t[ni] = fmaf(x, mrow[mi][r], t[ni]);
                }
#pragma unroll
        for (int ni = 0; ni < NI; ++ni) {
            t[ni] += __shfl_xor(t[ni], 16, 64);
            t[ni] += __shfl_xor(t[ni], 32, 64);
        }
        if (quad == 0) {
            const int sb = row0 >> 8;                       // sentence-batch
            const int base = (sb & 63) * 1024 + (sb >> 6) * 512;
#pragma unroll
            for (int ni = 0; ni < NI; ++ni)
                atomicAdd(rout + base + col0 + wn + ni * 16 + l15, t[ni]);
        }
        return;
    }

    float bv[NI];
    if constexpr (MODE == 0 || MODE == 3) {
#pragma unroll
        for (int ni = 0; ni < NI; ++ni)
            bv[ni] = bias ? bias[col0 + wn + ni * 16 + l15] : 0.f;
    } else {
#pragma unroll
        for (int ni = 0; ni < NI; ++ni) bv[ni] = 0.f;
    }

    if constexpr (MODE == 1) {
        __shared__ float red[NW][64];
        const int kb = b ^ maskXor;
        float mk[NI];
#pragma unroll
        for (int ni = 0; ni < NI; ++ni)
            mk[ni] = smask[kb * 256 + wn + ni * 16 + l15];
        float rm[4][4];
#pragma unroll
        for (int mi = 0; mi < 4; ++mi)
#pragma unroll
            for (int r = 0; r < 4; ++r) rm[mi][r] = -INFINITY;
#pragma unroll
        for (int mi = 0; mi < 4; ++mi)
#pragma unroll
            for (int r = 0; r < 4; ++r) {
                const int q = row0 + wm + mi * 16 + quad * 4 + r;
#pragma unroll
                for (int ni = 0; ni < NI; ++ni) {
                    const int j = wn + ni * 16 + l15;
                    float s = acc[mi][ni][r];
                    if (distW) {
                        int d = j - q;
                        d = d > MAX_DIST ? MAX_DIST : (d < -MAX_DIST ? -MAX_DIST : d);
                        s += distW[d + MAX_DIST];
                    }
                    if (diag && j == q) s = -INFINITY;
                    if (mk[ni] == 0.f) s = -1e9f;
                    acc[mi][ni][r] = s;
                    rm[mi][r] = fmaxf(rm[mi][r], s);
                }
            }
#pragma unroll
        for (int mi = 0; mi < 4; ++mi)
#pragma unroll
            for (int r = 0; r < 4; ++r) {
                float v = rm[mi][r];
                v = fmaxf(v, __shfl_xor(v, 1, 64));
                v = fmaxf(v, __shfl_xor(v, 2, 64));
                v = fmaxf(v, __shfl_xor(v, 4, 64));
                v = fmaxf(v, __shfl_xor(v, 8, 64));
                rm[mi][r] = v;
            }
        if (l15 == 0) {
#pragma unroll
            for (int mi = 0; mi < 4; ++mi)
#pragma unroll
                for (int r = 0; r < 4; ++r)
                    red[wave][mi * 16 + quad * 4 + r] = rm[mi][r];
        }
        __syncthreads();
#pragma unroll
        for (int mi = 0; mi < 4; ++mi)
#pragma unroll
            for (int r = 0; r < 4; ++r)
                rm[mi][r] = fmaxf(rm[mi][r],
                                  red[wave ^ 1][mi * 16 + quad * 4 + r]);
        float rs[4][4];
#pragma unroll
        for (int mi = 0; mi < 4; ++mi)
#pragma unroll
            for (int r = 0; r < 4; ++r) rs[mi][r] = 0.f;
#pragma unroll
        for (int mi = 0; mi < 4; ++mi)
#pragma unroll
            for (int ni = 0; ni < NI; ++ni)
#pragma unroll
                for (int r = 0; r < 4; ++r) {
                    float e = __expf(acc[mi][ni][r] - rm[mi][r]);
                    acc[mi][ni][r] = e;
                    rs[mi][r] += e;
                }
#pragma unroll
        for (int mi = 0; mi < 4; ++mi)
#pragma unroll
            for (int r = 0; r < 4; ++r) {
                float v = rs[mi][r];
                v += __shfl_xor(v, 1, 64);
                v += __shfl_xor(v, 2, 64);
                v += __shfl_xor(v, 4, 64);
                v += __shfl_xor(v, 8, 64);
                rs[mi][r] = v;
            }
        __syncthreads();
        if (l15 == 0) {
#pragma unroll
            for (int mi = 0; mi < 4; ++mi)
#pragma unroll
                for (int r = 0; r < 4; ++r)
                    red[wave][mi * 16 + quad * 4 + r] = rs[mi][r];
        }
        __syncthreads();
#pragma unroll
        for (int mi = 0; mi < 4; ++mi)
#pragma unroll
            for (int r = 0; r < 4; ++r) {
                const float tot = rs[mi][r] +
                                  red[wave ^ 1][mi * 16 + quad * 4 + r];
                const float inv = 1.f / tot;
#pragma unroll
                for (int ni = 0; ni < NI; ++ni)
                    acc[mi][ni][r] *= inv;
            }
        __syncthreads();
    }

    // coalesced bf16 epilogue: 32-row slabs through LDS, 16B packed stores
    {
        float* Ls = (float*)smem;                 // [32][257] fp32
        constexpr int LSW = 257;
        constexpr int SLABS = MT / 32;
        constexpr int CPT = 1024 / NT;            // chunks per thread per slab
        unsigned short* Cb = (unsigned short*)Cv + (long long)b * bsC;
#pragma unroll
        for (int h = 0; h < SLABS; ++h) {
            if ((wave >> 1) == (h >> 1)) {
                const int mi0 = (h & 1) * 2;
#pragma unroll
                for (int mm = 0; mm < 2; ++mm) {
#pragma unroll
                    for (int ni = 0; ni < NI; ++ni) {
#pragma unroll
                        for (int r = 0; r < 4; ++r) {
                            float x = acc[mi0 + mm][ni][r] + bv[ni];
                            if ((MODE == 0 || MODE == 3) && relu)
                                x = fmaxf(x, 0.f);
                            Ls[(mm * 16 + quad * 4 + r) * LSW +
                               wn + ni * 16 + l15] = x;
                        }
                    }
                }
            }
            __syncthreads();
#pragma unroll
            for (int it = 0; it < CPT; ++it) {
                const int c  = it * NT + tid;
                const int lr = c >> 5;           // /32 chunks-per-row
                const int cc = (c & 31) * 8;
                const float* src = &Ls[lr * LSW + cc];
                u16x8 u;
#pragma unroll
                for (int j = 0; j < 8; ++j) u[j] = f2bf(src[j]);
                *(u16x8*)(Cb + (long long)(row0 + h * 32 + lr) * ldc +
                          col0 + cc) = u;
            }
            if constexpr (MODE == 3) {
                // transposed store: tout[b][col0+c][row0 + h*32 + j0..j0+7]
#pragma unroll
                for (int it = 0; it < CPT; ++it) {
                    const int idx = it * NT + tid;       // 0..1023
                    const int c   = idx >> 2;            // 0..255
                    const int j0  = (idx & 3) * 8;       // 0,8,16,24
                    u16x8 u;
#pragma unroll
                    for (int j = 0; j < 8; ++j)
                        u[j] = f2bf(Ls[(j0 + j) * LSW + c]);
                    *(u16x8*)(tout + (long long)b * tbs +
                              (long long)(col0 + c) * 256 +
                              row0 + h * 32 + j0) = u;
                }
            }
            __syncthreads();
        }
    }
}

// ---------------------------------------------------------------------------
// All-6 weight convert+transpose: W fp32 [K,512] -> WT bf16 [512,K]
// ---------------------------------------------------------------------------
struct WC6 {
    const float* s[6];
    unsigned short* d[6];
    int K[6];
};
__global__ void wconv6_kernel(WC6 wc)
{
    const int z = blockIdx.z;
    const int K = wc.K[z];
    const int k0 = blockIdx.y * 32;
    if (k0 >= K) return;
    const float* src = wc.s[z];
    unsigned short* dst = wc.d[z];
    __shared__ float tile[32][33];
    const int n0 = blockIdx.x * 32;
#pragma unroll
    for (int i = 0; i < 4; ++i)
        tile[threadIdx.y + i * 8][threadIdx.x] =
            src[(long long)(k0 + threadIdx.y + i * 8) * 512 + n0 + threadIdx.x];
    __syncthreads();
#pragma unroll
    for (int i = 0; i < 4; ++i)
        dst[(long long)(n0 + threadIdx.y + i * 8) * K + k0 + threadIdx.x] =
            f2bf(tile[threadIdx.x][threadIdx.y + i * 8]);
}

// ---------------------------------------------------------------------------
// Vectorized x^T: CAT cols [0,512) of sentence s -> VTF[s][c][l].
// ---------------------------------------------------------------------------
__global__ __launch_bounds__(256) void btransv_kernel(
    const unsigned short* __restrict__ CAT, unsigned short* __restrict__ VTF)
{
    __shared__ unsigned short T[64 * 72];
    const int s  = blockIdx.z;
    const int c0 = blockIdx.x * 64;
    const int l0 = blockIdx.y * 64;
    const unsigned short* src = CAT + (long long)s * 256 * 1024;
    unsigned short* dst = VTF + (long long)s * 1024 * 256;
#pragma unroll
    for (int it = 0; it < 2; ++it) {
        const int idx = it * 256 + threadIdx.x;
        const int l   = idx >> 3;
        const int ch  = idx & 7;
        u16x8 v = *(const u16x8*)(src + (long long)(l0 + l) * 1024 +
                                  c0 + ch * 8);
        *(u16x8*)&T[l * 72 + ch * 8] = v;
    }
    __syncthreads();
#pragma unroll
    for (int it = 0; it < 2; ++it) {
        const int idx = it * 256 + threadIdx.x;
        const int c   = idx >> 3;
        const int ch2 = idx & 7;
        u16x8 u;
#pragma unroll
        for (int j = 0; j < 8; ++j)
            u[j] = T[(ch2 * 8 + j) * 72 + c];
        *(u16x8*)(dst + (long long)(c0 + c) * 256 + l0 + ch2 * 8) = u;
    }
}

// Embedding gather (both sentences) + mask + R32 zeroing
__global__ void embed_kernel(const int* __restrict__ prem_tok,
                             const int* __restrict__ hypo_tok,
                             const float* __restrict__ W,
                             unsigned short* __restrict__ cat,
                             float* __restrict__ mask,
                             float* __restrict__ R32)
{
    const int row = blockIdx.x;
    const int t   = threadIdx.x;
    const int tok = row < BL ? prem_tok[row] : hypo_tok[row - BL];
    if (t == 0) mask[row] = (tok != 0) ? 1.0f : 0.0f;
    if (row < 64) {
        float4 z = {0.f, 0.f, 0.f, 0.f};
        ((float4*)(R32 + row * 1024))[t]       = z;
        ((float4*)(R32 + row * 1024))[t + 128] = z;
    }
    float4 v = ((const float4*)(W + (long long)tok * EE))[t];
    ushort4 o;
    o.x = f2bf(v.x); o.y = f2bf(v.y); o.z = f2bf(v.z); o.w = f2bf(v.w);
    ((ushort4*)(cat + (long long)row * 1024))[t] = o;
}

// ---------------------------------------------------------------------------
// Fused aggregate tail: R32[b] -> MLP(1024->512) -> MLP(512->512) -> @Wo.
// ---------------------------------------------------------------------------
__global__ __launch_bounds__(512) void agg_kernel(
    const float* __restrict__ R32,
    const float* __restrict__ Wg1, const float* __restrict__ bg1,
    const float* __restrict__ Wg2, const float* __restrict__ bg2,
    const float* __restrict__ Wo, float* __restrict__ out)
{
    __shared__ float buf[1024];
    const int b = blockIdx.x, n = threadIdx.x;
    buf[n]       = R32[b * 1024 + n];
    buf[n + 512] = R32[b * 1024 + n + 512];
    __syncthreads();
    float a0 = 0.f, a1 = 0.f;
#pragma unroll 8
    for (int k = 0; k < 1024; k += 2) {
        a0 = fmaf(buf[k],     Wg1[(long long)k * 512 + n],       a0);
        a1 = fmaf(buf[k + 1], Wg1[(long long)(k + 1) * 512 + n], a1);
    }
    float h = fmaxf(a0 + a1 + bg1[n], 0.f);
    __syncthreads();
    buf[n] = h;
    __syncthreads();
    a0 = 0.f; a1 = 0.f;
#pragma unroll 8
    for (int k = 0; k < 512; k += 2) {
        a0 = fmaf(buf[k],     Wg2[(long long)k * 512 + n],       a0);
        a1 = fmaf(buf[k + 1], Wg2[(long long)(k + 1) * 512 + n], a1);
    }
    float g = fmaxf(a0 + a1 + bg2[n], 0.f);
    __syncthreads();
    buf[n] = g;
    __syncthreads();
    const int wave = n >> 6, lane = n & 63;
    if (wave < 3) {
        float acc = 0.f;
#pragma unroll
        for (int j = 0; j < 8; ++j) {
            int d = lane + j * 64;
            acc = fmaf(buf[d], Wo[d * 3 + wave], acc);
        }
#pragma unroll
        for (int st = 32; st > 0; st >>= 1)
            acc += __shfl_down(acc, st, 64);
        if (lane == 0) out[b * 3 + wave] = acc;
    }
}

// ---------------------------------------------------------------------------
// Host-side launcher
// ---------------------------------------------------------------------------
struct GemmArgs {
    const unsigned short *A0, *A1, *B;
    int K0, lda0, lda1, ldb;
    long long bsA0, bsA1, bsB;
    int bxor;
    const float* bias;
    void* C; int ldc; long long bsC;
    int M, N, K, relu, batch, shareAB;
    const float* smask; const float* distW; int diag; int maskXor;
    float* rout; const float* rmask;
    unsigned short* tout; long long tbs;
};

template <int MODE, int MT>
static inline void bgemm_launch(hipStream_t stream, const GemmArgs& a)
{
    dim3 grid(a.M / MT, a.N / 256, a.batch);
    bgemm_kernel<MODE, MT><<<grid, MT * 2, 0, stream>>>(
        a.A0, a.K0, a.lda0, a.bsA0, a.A1, a.lda1, a.bsA1,
        a.B, a.ldb, a.bsB, a.bxor, a.bias, a.C, a.ldc, a.bsC,
        a.K, a.relu, a.shareAB, a.smask, a.distW, a.diag, a.maskXor,
        a.rout, a.rmask, a.tout, a.tbs);
}

extern "C" void kernel_launch(void* const* d_in, const int* in_sizes, int n_in,
                              void* d_out, int out_size, void* d_ws, size_t ws_size,
                              hipStream_t stream)
{
    (void)in_sizes; (void)n_in; (void)out_size; (void)ws_size;

    const int*   prem_tok = (const int*)d_in[0];
    const int*   hypo_tok = (const int*)d_in[1];
    const float* embW = (const float*)d_in[2];
    const float* dW   = (const float*)d_in[3];
    const float* Ws1  = (const float*)d_in[4];
    const float* bs1  = (const float*)d_in[5];
    const float* Ws2  = (const float*)d_in[6];
    const float* bs2  = (const float*)d_in[7];
    const float* Wa1  = (const float*)d_in[8];
    const float* ba1  = (const float*)d_in[9];
    const float* Wa2  = (const float*)d_in[10];
    const float* ba2  = (const float*)d_in[11];
    const float* Wc1  = (const float*)d_in[12];
    const float* bc1  = (const float*)d_in[13];
    const float* Wc2  = (const float*)d_in[14];
    const float* bc2  = (const float*)d_in[15];
    const float* Wg1  = (const float*)d_in[16];
    const float* bg1  = (const float*)d_in[17];
    const float* Wg2  = (const float*)d_in[18];
    const float* bg2  = (const float*)d_in[19];
    const float* Wo   = (const float*)d_in[20];
    float* out = (float*)d_out;

    // ---- workspace carve-up (bytes) ----
    char* ws = (char*)d_ws;
    size_t off = 0;
    auto alloc = [&](size_t bytes) {
        char* p = ws + off; off += (bytes + 255) & ~(size_t)255; return p;
    };
    unsigned short* CAT  = (unsigned short*)alloc((size_t)BL2 * 1024 * 2);
    unsigned short* VTF  = (unsigned short*)alloc((size_t)128 * 1024 * 256 * 2);
    unsigned short* Hb   = (unsigned short*)alloc((size_t)BL2 * 512 * 2);
    unsigned short* Q    = (unsigned short*)alloc((size_t)BL2 * 512 * 2);
    unsigned short* ATT  = (unsigned short*)alloc((size_t)BL2 * 1024 * 2);
    unsigned short* SP   = (unsigned short*)alloc((size_t)128 * LL * LL * 2);
    float*          MASK = (float*)alloc((size_t)BL2 * 4);
    float*          R32  = (float*)alloc((size_t)BB * 1024 * 4);
    unsigned short* WTs1 = (unsigned short*)alloc((size_t)512 * 512 * 2);
    unsigned short* WTs2 = (unsigned short*)alloc((size_t)512 * 512 * 2);
    unsigned short* WTa1 = (unsigned short*)alloc((size_t)1024 * 512 * 2);
    unsigned short* WTa2 = (unsigned short*)alloc((size_t)512 * 512 * 2);
    unsigned short* WTc1 = (unsigned short*)alloc((size_t)2048 * 512 * 2);
    unsigned short* WTc2 = (unsigned short*)alloc((size_t)512 * 512 * 2);

    const long long bsQ = (long long)LL * DD;       // 131072
    const long long bsS = (long long)LL * LL;       // 65536
    const long long bsC = (long long)LL * 1024;     // 262144
    const long long bsV = (long long)1024 * 256;    // VTF batch stride

    dim3 tb(32, 8);

    // 0. weights -> [512, K] bf16
    WC6 wc;
    wc.s[0] = Ws1; wc.d[0] = WTs1; wc.K[0] = 512;
    wc.s[1] = Ws2; wc.d[1] = WTs2; wc.K[1] = 512;
    wc.s[2] = Wa1; wc.d[2] = WTa1; wc.K[2] = 1024;
    wc.s[3] = Wa2; wc.d[3] = WTa2; wc.K[3] = 512;
    wc.s[4] = Wc1; wc.d[4] = WTc1; wc.K[4] = 2048;
    wc.s[5] = Wc2; wc.d[5] = WTc2; wc.K[5] = 512;
    wconv6_kernel<<<dim3(16, 64, 6), tb, 0, stream>>>(wc);

    // 1. embeddings + masks + R32 zero
    embed_kernel<<<BL2, 128, 0, stream>>>(prem_tok, hypo_tok, embW, CAT,
                                          MASK, R32);

    GemmArgs a = {};

    // 2. self MLP (merged M=32768)
    a = {}; a.A0 = CAT; a.K0 = 512; a.lda0 = 1024; a.B = WTs1; a.ldb = 512;
    a.bias = bs1; a.C = Hb; a.ldc = 512; a.M = BL2; a.N = 512; a.K = 512;
    a.relu = 1; a.batch = 1;
    bgemm_launch<0, 128>(stream, a);
    a = {}; a.A0 = Hb; a.K0 = 512; a.lda0 = 512; a.B = WTs2; a.ldb = 512;
    a.bias = bs2; a.C = Q; a.ldc = 512; a.M = BL2; a.N = 512; a.K = 512;
    a.relu = 1; a.batch = 1;
    bgemm_launch<0, 128>(stream, a);

    // x^T per sentence -> VTF rows [0,512)
    btransv_kernel<<<dim3(8, 4, 128), 256, 0, stream>>>(CAT, VTF);

    // 3. self scores + fused softmax -> SP  (MT=256, A==B staged once)
    a = {}; a.A0 = Q; a.K0 = 512; a.lda0 = 512; a.bsA0 = bsQ;
    a.B = Q; a.ldb = 512; a.bsB = bsQ; a.bxor = 0; a.shareAB = 1;
    a.C = SP; a.ldc = 256; a.bsC = bsS; a.M = 256; a.N = 256; a.K = 512;
    a.batch = 128; a.smask = MASK; a.distW = dW; a.diag = 1; a.maskXor = 0;
    bgemm_launch<1, 256>(stream, a);

    // 4. ctx = att @ x -> CAT cols [512,1024) + transposed -> VTF rows
    //    [512,1024) (MODE 3, MT=256)
    a = {}; a.A0 = SP; a.K0 = 256; a.lda0 = 256; a.bsA0 = bsS;
    a.B = VTF; a.ldb = 256; a.bsB = bsV;
    a.C = CAT + 512; a.ldc = 1024; a.bsC = bsC;
    a.M = 256; a.N = 512; a.K = 256; a.batch = 128;
    a.tout = VTF + (size_t)512 * 256; a.tbs = bsV;
    bgemm_launch<3, 256>(stream, a);

    // 5. inter projections (merged)
    a = {}; a.A0 = CAT; a.K0 = 1024; a.lda0 = 1024; a.B = WTa1; a.ldb = 1024;
    a.bias = ba1; a.C = Hb; a.ldc = 512; a.M = BL2; a.N = 512; a.K = 1024;
    a.relu = 1; a.batch = 1;
    bgemm_launch<0, 128>(stream, a);
    a = {}; a.A0 = Hb; a.K0 = 512; a.lda0 = 512; a.B = WTa2; a.ldb = 512;
    a.bias = ba2; a.C = Q; a.ldc = 512; a.M = BL2; a.N = 512; a.K = 512;
    a.relu = 1; a.batch = 1;
    bgemm_launch<0, 128>(stream, a);

    // 6. z and z^T + fused row softmax (key = sentence b^64) -> SP (MT=256)
    a = {}; a.A0 = Q; a.K0 = 512; a.lda0 = 512; a.bsA0 = bsQ;
    a.B = Q; a.ldb = 512; a.bsB = bsQ; a.bxor = 64;
    a.C = SP; a.ldc = 256; a.bsC = bsS; a.M = 256; a.N = 256; a.K = 512;
    a.batch = 128; a.smask = MASK; a.distW = nullptr; a.diag = 0; a.maskXor = 64;
    bgemm_launch<1, 256>(stream, a);

    // 7. merged attend: ATT[b] = SP[b] @ V[b^64]  (MT=256)
    a = {}; a.A0 = SP; a.K0 = 256; a.lda0 = 256; a.bsA0 = bsS;
    a.B = VTF; a.ldb = 256; a.bsB = bsV; a.bxor = 64;
    a.C = ATT; a.ldc = 1024; a.bsC = bsC;
    a.M = 256; a.N = 1024; a.K = 256; a.batch = 128;
    bgemm_launch<0, 256>(stream, a);

    // 8. compare MLP layer 1 (K = 2048 via concat)
    a = {}; a.A0 = CAT; a.K0 = 1024; a.lda0 = 1024;
    a.A1 = ATT; a.lda1 = 1024;
    a.B = WTc1; a.ldb = 2048; a.bias = bc1;
    a.C = Hb; a.ldc = 512; a.M = BL2; a.N = 512; a.K = 2048;
    a.relu = 1; a.batch = 1;
    bgemm_launch<0, 128>(stream, a);

    // 9. compare MLP layer 2 + fused masked position-sum -> R32
    a = {}; a.A0 = Hb; a.K0 = 512; a.lda0 = 512; a.B = WTc2; a.ldb = 512;
    a.bias = bc2; a.M = BL2; a.N = 512; a.K = 512; a.relu = 1; a.batch = 1;
    a.rout = R32; a.rmask = MASK; a.C = Hb; // C unused in MODE 2
    bgemm_launch<2, 128>(stream, a);

    // 10. fused aggregate MLP + output
    agg_kernel<<<64, 512, 0, stream>>>(R32, Wg1, bg1, Wg2, bg2, Wo, out);
}

// Round 10
// 625.715 us; speedup vs baseline: 1.1747x; 1.1747x over previous
//
#include <hip/hip_runtime.h>
#include <math.h>

#define BB   64
#define LL   256
#define EE   512
#define DD   512
#define BL   (BB * LL)      // 16384
#define BL2  (2 * BL)       // 32768 (prem rows then hypo rows)
#define MAX_DIST 11

typedef __attribute__((ext_vector_type(8))) short bf16x8;
typedef __attribute__((ext_vector_type(8))) unsigned short u16x8;
typedef __attribute__((ext_vector_type(4))) float f32x4;

__device__ __forceinline__ float bf2f(unsigned short u) {
    union { unsigned int u; float f; } v; v.u = ((unsigned int)u) << 16; return v.f;
}
__device__ __forceinline__ unsigned short f2bf(float f) {
    union { float f; unsigned int u; } v; v.f = f;
    unsigned int r = v.u + 0x7FFF + ((v.u >> 16) & 1);   // RNE
    return (unsigned short)(r >> 16);
}

#define GLOAD16(g, l)                                                          \
    __builtin_amdgcn_global_load_lds(                                          \
        (const __attribute__((address_space(1))) void*)(g),                    \
        (__attribute__((address_space(3))) void*)(l), 16, 0, 0)

// ---------------------------------------------------------------------------
// bf16 MFMA GEMM, BK=64, tile 128x256, 4 waves (wave tile 64x128).
// MODE 0: C = act([A0|A1]*B^T + bias), bf16 out, coalesced LDS epilogue.
// MODE 1: fused row-softmax epilogue (N==256): dist-bias/diag/key-mask,
//         full-row softmax (shuffle + cross-wave LDS), bf16 probs out.
// MODE 2: masked row-reduce epilogue: relu(acc+bias)*mask[row] summed over
//         rows, atomicAdd into rout [64,1024]; no C write.
// SHARE (compile-time): A rows are contained in the staged B tile (requires
//   A==B buffer, N==256, col0==0) -> skip A staging, read A frags from Bs
//   at global row row0+r.  Used only for self-scores Q@Q^T.
// B batch index is (b ^ bxor).
// Grid (M/128, N/256, batch): A-slab sharers land on one XCD (L2 reuse).
// LDS: rows of 64 bf16 = 8 x 16B chunks, chunk g of row r at slot g^(r&7).
// ---------------------------------------------------------------------------
template <int MODE, bool SHARE = false>
__global__ __launch_bounds__(256, 2) void bgemm_kernel(
    const unsigned short* __restrict__ A0, int K0, int lda0, long long bsA0,
    const unsigned short* __restrict__ A1, int lda1, long long bsA1,
    const unsigned short* __restrict__ B, int ldb, long long bsB, int bxor,
    const float* __restrict__ bias,
    void* __restrict__ Cv, int ldc, long long bsC,
    int K, int relu,
    const float* __restrict__ smask, const float* __restrict__ distW,
    int diag, int maskXor,
    float* __restrict__ rout, const float* __restrict__ rmask)
{
    constexpr int BN = 256;
    constexpr int NI = 8;
    __shared__ unsigned short smem[(128 + BN) * 64];
    unsigned short* As = smem;
    unsigned short* Bs = smem + 128 * 64;

    const int tid  = threadIdx.x;
    const int wave = tid >> 6;
    const int lane = tid & 63;
    const int quad = lane >> 4;
    const int l15  = lane & 15;
    const int wm   = (wave >> 1) * 64;
    const int wn   = (wave & 1) * 128;
    const int row0 = blockIdx.x * 128;
    const int col0 = blockIdx.y * BN;
    const int b    = blockIdx.z;

    const unsigned short* A0b = A0 + (long long)b * bsA0;
    const unsigned short* A1b = A1 ? (A1 + (long long)b * bsA1) : nullptr;
    const unsigned short* Bb  = B + (long long)(b ^ bxor) * bsB;

    f32x4 acc[4][NI];
#pragma unroll
    for (int i = 0; i < 4; ++i)
#pragma unroll
        for (int j = 0; j < NI; ++j)
            acc[i][j] = (f32x4){0.f, 0.f, 0.f, 0.f};

    for (int kk = 0; kk < K; kk += 64) {
        if constexpr (!SHARE) {
            const unsigned short* Ap; int lda, kloc;
            if (kk < K0) { Ap = A0b; lda = lda0; kloc = kk; }
            else         { Ap = A1b; lda = lda1; kloc = kk - K0; }
#pragma unroll
            for (int it = 0; it < 4; ++it) {
                const int c   = it * 256 + tid;
                const int row = c >> 3;
                const int kch = (c & 7) ^ (row & 7);
                GLOAD16(Ap + (long long)(row0 + row) * lda + kloc + kch * 8,
                        (char*)As + c * 16);
            }
        }
#pragma unroll
        for (int it = 0; it < 8; ++it) {
            const int c   = it * 256 + tid;
            const int row = c >> 3;
            const int kch = (c & 7) ^ (row & 7);
            GLOAD16(Bb + (long long)(col0 + row) * ldb + kk + kch * 8,
                    (char*)Bs + c * 16);
        }
        __syncthreads();

#pragma unroll
        for (int s = 0; s < 2; ++s) {
            bf16x8 fa[4], fb[NI];
#pragma unroll
            for (int mi = 0; mi < 4; ++mi) {
                if constexpr (SHARE) {
                    const int r = row0 + wm + mi * 16 + l15;  // global row in Bs
                    const int slot = (s * 4 + quad) ^ (r & 7);
                    fa[mi] = *(const bf16x8*)&Bs[(r * 8 + slot) * 8];
                } else {
                    const int r = wm + mi * 16 + l15;
                    const int slot = (s * 4 + quad) ^ (r & 7);
                    fa[mi] = *(const bf16x8*)&As[(r * 8 + slot) * 8];
                }
            }
#pragma unroll
            for (int ni = 0; ni < NI; ++ni) {
                const int r = wn + ni * 16 + l15;
                const int slot = (s * 4 + quad) ^ (r & 7);
                fb[ni] = *(const bf16x8*)&Bs[(r * 8 + slot) * 8];
            }
#pragma unroll
            for (int mi = 0; mi < 4; ++mi)
#pragma unroll
                for (int ni = 0; ni < NI; ++ni)
                    acc[mi][ni] = __builtin_amdgcn_mfma_f32_16x16x32_bf16(
                        fa[mi], fb[ni], acc[mi][ni], 0, 0, 0);
        }
        __syncthreads();
    }

    if constexpr (MODE == 2) {
        float bv[NI];
#pragma unroll
        for (int ni = 0; ni < NI; ++ni)
            bv[ni] = bias[col0 + wn + ni * 16 + l15];
        float mrow[4][4];
#pragma unroll
        for (int mi = 0; mi < 4; ++mi)
#pragma unroll
            for (int r = 0; r < 4; ++r)
                mrow[mi][r] = rmask[row0 + wm + mi * 16 + quad * 4 + r];
        float t[NI];
#pragma unroll
        for (int ni = 0; ni < NI; ++ni) t[ni] = 0.f;
#pragma unroll
        for (int mi = 0; mi < 4; ++mi)
#pragma unroll
            for (int ni = 0; ni < NI; ++ni)
#pragma unroll
                for (int r = 0; r < 4; ++r) {
                    float x = fmaxf(acc[mi][ni][r] + bv[ni], 0.f);
                    t[ni] = fmaf(x, mrow[mi][r], t[ni]);
                }
#pragma unroll
        for (int ni = 0; ni < NI; ++ni) {
            t[ni] += __shfl_xor(t[ni], 16, 64);
            t[ni] += __shfl_xor(t[ni], 32, 64);
        }
        if (quad == 0) {
            const int sb = row0 >> 8;                       // sentence-batch
            const int base = (sb & 63) * 1024 + (sb >> 6) * 512;
#pragma unroll
            for (int ni = 0; ni < NI; ++ni)
                atomicAdd(rout + base + col0 + wn + ni * 16 + l15, t[ni]);
        }
        return;
    }

    float bv[NI];
    if constexpr (MODE == 0) {
#pragma unroll
        for (int ni = 0; ni < NI; ++ni)
            bv[ni] = bias ? bias[col0 + wn + ni * 16 + l15] : 0.f;
    } else {
#pragma unroll
        for (int ni = 0; ni < NI; ++ni) bv[ni] = 0.f;
    }

    if constexpr (MODE == 1) {
        __shared__ float red[4][64];
        const int kb = b ^ maskXor;
        float mk[NI];
#pragma unroll
        for (int ni = 0; ni < NI; ++ni)
            mk[ni] = smask[kb * 256 + wn + ni * 16 + l15];
        float rm[4][4];
#pragma unroll
        for (int mi = 0; mi < 4; ++mi)
#pragma unroll
            for (int r = 0; r < 4; ++r) rm[mi][r] = -INFINITY;
#pragma unroll
        for (int mi = 0; mi < 4; ++mi)
#pragma unroll
            for (int r = 0; r < 4; ++r) {
                const int q = row0 + wm + mi * 16 + quad * 4 + r;
#pragma unroll
                for (int ni = 0; ni < NI; ++ni) {
                    const int j = wn + ni * 16 + l15;
                    float s = acc[mi][ni][r];
                    if (distW) {
                        int d = j - q;
                        d = d > MAX_DIST ? MAX_DIST : (d < -MAX_DIST ? -MAX_DIST : d);
                        s += distW[d + MAX_DIST];
                    }
                    if (diag && j == q) s = -INFINITY;
                    if (mk[ni] == 0.f) s = -1e9f;
                    acc[mi][ni][r] = s;
                    rm[mi][r] = fmaxf(rm[mi][r], s);
                }
            }
#pragma unroll
        for (int mi = 0; mi < 4; ++mi)
#pragma unroll
            for (int r = 0; r < 4; ++r) {
                float v = rm[mi][r];
                v = fmaxf(v, __shfl_xor(v, 1, 64));
                v = fmaxf(v, __shfl_xor(v, 2, 64));
                v = fmaxf(v, __shfl_xor(v, 4, 64));
                v = fmaxf(v, __shfl_xor(v, 8, 64));
                rm[mi][r] = v;
            }
        if (l15 == 0) {
#pragma unroll
            for (int mi = 0; mi < 4; ++mi)
#pragma unroll
                for (int r = 0; r < 4; ++r)
                    red[wave][mi * 16 + quad * 4 + r] = rm[mi][r];
        }
        __syncthreads();
#pragma unroll
        for (int mi = 0; mi < 4; ++mi)
#pragma unroll
            for (int r = 0; r < 4; ++r)
                rm[mi][r] = fmaxf(rm[mi][r],
                                  red[wave ^ 1][mi * 16 + quad * 4 + r]);
        float rs[4][4];
#pragma unroll
        for (int mi = 0; mi < 4; ++mi)
#pragma unroll
            for (int r = 0; r < 4; ++r) rs[mi][r] = 0.f;
#pragma unroll
        for (int mi = 0; mi < 4; ++mi)
#pragma unroll
            for (int ni = 0; ni < NI; ++ni)
#pragma unroll
                for (int r = 0; r < 4; ++r) {
                    float e = __expf(acc[mi][ni][r] - rm[mi][r]);
                    acc[mi][ni][r] = e;
                    rs[mi][r] += e;
                }
#pragma unroll
        for (int mi = 0; mi < 4; ++mi)
#pragma unroll
            for (int r = 0; r < 4; ++r) {
                float v = rs[mi][r];
                v += __shfl_xor(v, 1, 64);
                v += __shfl_xor(v, 2, 64);
                v += __shfl_xor(v, 4, 64);
                v += __shfl_xor(v, 8, 64);
                rs[mi][r] = v;
            }
        __syncthreads();
        if (l15 == 0) {
#pragma unroll
            for (int mi = 0; mi < 4; ++mi)
#pragma unroll
                for (int r = 0; r < 4; ++r)
                    red[wave][mi * 16 + quad * 4 + r] = rs[mi][r];
        }
        __syncthreads();
#pragma unroll
        for (int mi = 0; mi < 4; ++mi)
#pragma unroll
            for (int r = 0; r < 4; ++r) {
                const float tot = rs[mi][r] +
                                  red[wave ^ 1][mi * 16 + quad * 4 + r];
                const float inv = 1.f / tot;
#pragma unroll
                for (int ni = 0; ni < NI; ++ni)
                    acc[mi][ni][r] *= inv;
            }
        __syncthreads();
    }

    // coalesced bf16 epilogue: 32-row slabs through LDS, 16B packed stores
    {
        float* Ls = (float*)smem;                 // [32][257] fp32
        constexpr int LSW = 257;
        unsigned short* Cb = (unsigned short*)Cv + (long long)b * bsC;
#pragma unroll
        for (int h = 0; h < 4; ++h) {
            if ((wave >> 1) == (h >> 1)) {
                const int mi0 = (h & 1) * 2;
#pragma unroll
                for (int mm = 0; mm < 2; ++mm) {
#pragma unroll
                    for (int ni = 0; ni < NI; ++ni) {
#pragma unroll
                        for (int r = 0; r < 4; ++r) {
                            float x = acc[mi0 + mm][ni][r] + bv[ni];
                            if (MODE == 0 && relu) x = fmaxf(x, 0.f);
                            Ls[(mm * 16 + quad * 4 + r) * LSW +
                               wn + ni * 16 + l15] = x;
                        }
                    }
                }
            }
            __syncthreads();
#pragma unroll
            for (int it = 0; it < 4; ++it) {
                const int c  = it * 256 + tid;
                const int lr = c >> 5;           // /32 chunks-per-row
                const int cc = (c & 31) * 8;
                const float* src = &Ls[lr * LSW + cc];
                u16x8 u;
#pragma unroll
                for (int j = 0; j < 8; ++j) u[j] = f2bf(src[j]);
                *(u16x8*)(Cb + (long long)(row0 + h * 32 + lr) * ldc +
                          col0 + cc) = u;
            }
            __syncthreads();
        }
    }
}

// ---------------------------------------------------------------------------
// All-6 weight convert+transpose: W fp32 [K,512] -> WT bf16 [512,K]
// ---------------------------------------------------------------------------
struct WC6 {
    const float* s[6];
    unsigned short* d[6];
    int K[6];
};
__global__ void wconv6_kernel(WC6 wc)
{
    const int z = blockIdx.z;
    const int K = wc.K[z];
    const int k0 = blockIdx.y * 32;
    if (k0 >= K) return;
    const float* src = wc.s[z];
    unsigned short* dst = wc.d[z];
    __shared__ float tile[32][33];
    const int n0 = blockIdx.x * 32;
#pragma unroll
    for (int i = 0; i < 4; ++i)
        tile[threadIdx.y + i * 8][threadIdx.x] =
            src[(long long)(k0 + threadIdx.y + i * 8) * 512 + n0 + threadIdx.x];
    __syncthreads();
#pragma unroll
    for (int i = 0; i < 4; ++i)
        dst[(long long)(n0 + threadIdx.y + i * 8) * K + k0 + threadIdx.x] =
            f2bf(tile[threadIdx.x][threadIdx.y + i * 8]);
}

// Per-batch bf16 transpose: src batch (bz^bxor) rows [256][lds_] cols c0..C
__global__ void btrans_kernel(const unsigned short* __restrict__ src, int lds_,
                              unsigned short* __restrict__ dst, int C, int bxor)
{
    __shared__ unsigned short tile[32][33];
    const int bz = blockIdx.z;
    const int bs = bz ^ bxor;
    const int c0 = blockIdx.x * 32, l0 = blockIdx.y * 32;
    const unsigned short* s = src + (long long)bs * 256 * lds_;
    unsigned short* d = dst + (long long)bz * C * 256;
#pragma unroll
    for (int i = 0; i < 4; ++i)
        tile[threadIdx.y + i * 8][threadIdx.x] =
            s[(long long)(l0 + threadIdx.y + i * 8) * lds_ + c0 + threadIdx.x];
    __syncthreads();
#pragma unroll
    for (int i = 0; i < 4; ++i)
        d[(long long)(c0 + threadIdx.y + i * 8) * 256 + l0 + threadIdx.x] =
            tile[threadIdx.x][threadIdx.y + i * 8];
}

// Embedding gather (both sentences) + mask
__global__ void embed_kernel(const int* __restrict__ prem_tok,
                             const int* __restrict__ hypo_tok,
                             const float* __restrict__ W,
                             unsigned short* __restrict__ cat,
                             float* __restrict__ mask)
{
    const int row = blockIdx.x;
    const int t   = threadIdx.x;
    const int tok = row < BL ? prem_tok[row] : hypo_tok[row - BL];
    if (t == 0) mask[row] = (tok != 0) ? 1.0f : 0.0f;
    float4 v = ((const float4*)(W + (long long)tok * EE))[t];
    ushort4 o;
    o.x = f2bf(v.x); o.y = f2bf(v.y); o.z = f2bf(v.z); o.w = f2bf(v.w);
    ((ushort4*)(cat + (long long)row * 1024))[t] = o;
}

// Parallel small fp32 MLP layer: grid (8, BB), block 256
__global__ __launch_bounds__(256) void mlp_par_kernel(
    const float* __restrict__ X, const float* __restrict__ W,
    const float* __restrict__ bias, float* __restrict__ Y, int Kin)
{
    __shared__ float red[4][64];
    const int b  = blockIdx.y;
    const int n  = blockIdx.x * 64 + (threadIdx.x & 63);
    const int ts = threadIdx.x >> 6;
    const int kc = Kin >> 2;
    const float* x = X + (long long)b * Kin + ts * kc;
    const float* w = W + (long long)(ts * kc) * 512 + n;
    float a0 = 0.f, a1 = 0.f;
#pragma unroll 8
    for (int k = 0; k < kc; k += 2) {
        a0 = fmaf(x[k],     w[(long long)k * 512],       a0);
        a1 = fmaf(x[k + 1], w[(long long)(k + 1) * 512], a1);
    }
    red[ts][threadIdx.x & 63] = a0 + a1;
    __syncthreads();
    if (ts == 0) {
        float v = red[0][threadIdx.x] + red[1][threadIdx.x] +
                  red[2][threadIdx.x] + red[3][threadIdx.x] + bias[n];
        Y[b * 512 + n] = fmaxf(v, 0.f);
    }
}

// Final output: one wave per (b,o).  grid 48 x 256 thr = 192 waves.
__global__ void out_kernel(const float* __restrict__ G,
                           const float* __restrict__ Wo,
                           float* __restrict__ out)
{
    const int wid  = blockIdx.x * 4 + (threadIdx.x >> 6);
    const int lane = threadIdx.x & 63;
    const int b = wid / 3, o = wid % 3;
    float acc = 0.f;
#pragma unroll
    for (int j = 0; j < 8; ++j) {
        int d = lane + j * 64;
        acc = fmaf(G[b * DD + d], Wo[d * 3 + o], acc);
    }
#pragma unroll
    for (int st = 32; st > 0; st >>= 1)
        acc += __shfl_down(acc, st, 64);
    if (lane == 0) out[wid] = acc;
}

// ---------------------------------------------------------------------------
// Host-side launcher
// ---------------------------------------------------------------------------
struct GemmArgs {
    const unsigned short *A0, *A1, *B;
    int K0, lda0, lda1, ldb;
    long long bsA0, bsA1, bsB;
    int bxor;
    const float* bias;
    void* C; int ldc; long long bsC;
    int M, N, K, relu, batch;
    const float* smask; const float* distW; int diag; int maskXor;
    float* rout; const float* rmask;
};

template <int MODE, bool SHARE = false>
static inline void bgemm_launch(hipStream_t stream, const GemmArgs& a)
{
    dim3 grid(a.M / 128, a.N / 256, a.batch);
    bgemm_kernel<MODE, SHARE><<<grid, 256, 0, stream>>>(
        a.A0, a.K0, a.lda0, a.bsA0, a.A1, a.lda1, a.bsA1,
        a.B, a.ldb, a.bsB, a.bxor, a.bias, a.C, a.ldc, a.bsC,
        a.K, a.relu, a.smask, a.distW, a.diag, a.maskXor, a.rout, a.rmask);
}

extern "C" void kernel_launch(void* const* d_in, const int* in_sizes, int n_in,
                              void* d_out, int out_size, void* d_ws, size_t ws_size,
                              hipStream_t stream)
{
    (void)in_sizes; (void)n_in; (void)out_size; (void)ws_size;

    const int*   prem_tok = (const int*)d_in[0];
    const int*   hypo_tok = (const int*)d_in[1];
    const float* embW = (const float*)d_in[2];
    const float* dW   = (const float*)d_in[3];
    const float* Ws1  = (const float*)d_in[4];
    const float* bs1  = (const float*)d_in[5];
    const float* Ws2  = (const float*)d_in[6];
    const float* bs2  = (const float*)d_in[7];
    const float* Wa1  = (const float*)d_in[8];
    const float* ba1  = (const float*)d_in[9];
    const float* Wa2  = (const float*)d_in[10];
    const float* ba2  = (const float*)d_in[11];
    const float* Wc1  = (const float*)d_in[12];
    const float* bc1  = (const float*)d_in[13];
    const float* Wc2  = (const float*)d_in[14];
    const float* bc2  = (const float*)d_in[15];
    const float* Wg1  = (const float*)d_in[16];
    const float* bg1  = (const float*)d_in[17];
    const float* Wg2  = (const float*)d_in[18];
    const float* bg2  = (const float*)d_in[19];
    const float* Wo   = (const float*)d_in[20];
    float* out = (float*)d_out;

    // ---- workspace carve-up (bytes) ----
    char* ws = (char*)d_ws;
    size_t off = 0;
    auto alloc = [&](size_t bytes) {
        char* p = ws + off; off += (bytes + 255) & ~(size_t)255; return p;
    };
    unsigned short* CAT  = (unsigned short*)alloc((size_t)BL2 * 1024 * 2);
    unsigned short* VTF  = (unsigned short*)alloc((size_t)128 * 1024 * 256 * 2);
    unsigned short* Hb   = (unsigned short*)alloc((size_t)BL2 * 512 * 2);
    unsigned short* Q    = (unsigned short*)alloc((size_t)BL2 * 512 * 2);
    unsigned short* ATT  = (unsigned short*)alloc((size_t)BL2 * 1024 * 2);
    unsigned short* SP   = (unsigned short*)alloc((size_t)128 * LL * LL * 2);
    float*          MASK = (float*)alloc((size_t)BL2 * 4);
    float*          R32  = (float*)alloc((size_t)BB * 1024 * 4);
    float*          H64  = (float*)alloc((size_t)BB * 512 * 4);
    float*          G    = (float*)alloc((size_t)BB * 512 * 4);
    unsigned short* WTs1 = (unsigned short*)alloc((size_t)512 * 512 * 2);
    unsigned short* WTs2 = (unsigned short*)alloc((size_t)512 * 512 * 2);
    unsigned short* WTa1 = (unsigned short*)alloc((size_t)1024 * 512 * 2);
    unsigned short* WTa2 = (unsigned short*)alloc((size_t)512 * 512 * 2);
    unsigned short* WTc1 = (unsigned short*)alloc((size_t)2048 * 512 * 2);
    unsigned short* WTc2 = (unsigned short*)alloc((size_t)512 * 512 * 2);

    const long long bsQ = (long long)LL * DD;       // 131072
    const long long bsS = (long long)LL * LL;       // 65536
    const long long bsC = (long long)LL * 1024;     // 262144
    const long long bsV = (long long)1024 * 256;    // VTF batch stride (full)

    dim3 tb(32, 8);

    // 0. weights -> [512, K] bf16; zero R32 accumulator
    WC6 wc;
    wc.s[0] = Ws1; wc.d[0] = WTs1; wc.K[0] = 512;
    wc.s[1] = Ws2; wc.d[1] = WTs2; wc.K[1] = 512;
    wc.s[2] = Wa1; wc.d[2] = WTa1; wc.K[2] = 1024;
    wc.s[3] = Wa2; wc.d[3] = WTa2; wc.K[3] = 512;
    wc.s[4] = Wc1; wc.d[4] = WTc1; wc.K[4] = 2048;
    wc.s[5] = Wc2; wc.d[5] = WTc2; wc.K[5] = 512;
    wconv6_kernel<<<dim3(16, 64, 6), tb, 0, stream>>>(wc);
    hipMemsetAsync(R32, 0, (size_t)BB * 1024 * 4, stream);

    // 1. embeddings + masks
    embed_kernel<<<BL2, 128, 0, stream>>>(prem_tok, hypo_tok, embW, CAT, MASK);

    GemmArgs a = {};

    // 2. self MLP (merged M=32768)
    a = {}; a.A0 = CAT; a.K0 = 512; a.lda0 = 1024; a.B = WTs1; a.ldb = 512;
    a.bias = bs1; a.C = Hb; a.ldc = 512; a.M = BL2; a.N = 512; a.K = 512;
    a.relu = 1; a.batch = 1;
    bgemm_launch<0>(stream, a);
    a = {}; a.A0 = Hb; a.K0 = 512; a.lda0 = 512; a.B = WTs2; a.ldb = 512;
    a.bias = bs2; a.C = Q; a.ldc = 512; a.M = BL2; a.N = 512; a.K = 512;
    a.relu = 1; a.batch = 1;
    bgemm_launch<0>(stream, a);

    // x^T per sentence -> VTF area [128][512][256]
    btrans_kernel<<<dim3(16, 8, 128), tb, 0, stream>>>(CAT, 1024, VTF, 512, 0);

    // 3. self scores + fused softmax -> SP  (SHARE: A==B, skip A staging)
    a = {}; a.A0 = Q; a.K0 = 512; a.lda0 = 512; a.bsA0 = bsQ;
    a.B = Q; a.ldb = 512; a.bsB = bsQ; a.bxor = 0;
    a.C = SP; a.ldc = 256; a.bsC = bsS; a.M = 256; a.N = 256; a.K = 512;
    a.batch = 128; a.smask = MASK; a.distW = dW; a.diag = 1; a.maskXor = 0;
    bgemm_launch<1, true>(stream, a);

    // 4. ctx = att @ x -> CAT cols [512,1024)
    a = {}; a.A0 = SP; a.K0 = 256; a.lda0 = 256; a.bsA0 = bsS;
    a.B = VTF; a.ldb = 256; a.bsB = (long long)512 * 256;
    a.C = CAT + 512; a.ldc = 1024; a.bsC = bsC;
    a.M = 256; a.N = 512; a.K = 256; a.batch = 128;
    bgemm_launch<0>(stream, a);

    // 5. full V^T, cross-ordered (batch z holds sentence z^64)
    btrans_kernel<<<dim3(32, 8, 128), tb, 0, stream>>>(CAT, 1024, VTF, 1024, 64);

    // 6. inter projections (merged)
    a = {}; a.A0 = CAT; a.K0 = 1024; a.lda0 = 1024; a.B = WTa1; a.ldb = 1024;
    a.bias = ba1; a.C = Hb; a.ldc = 512; a.M = BL2; a.N = 512; a.K = 1024;
    a.relu = 1; a.batch = 1;
    bgemm_launch<0>(stream, a);
    a = {}; a.A0 = Hb; a.K0 = 512; a.lda0 = 512; a.B = WTa2; a.ldb = 512;
    a.bias = ba2; a.C = Q; a.ldc = 512; a.M = BL2; a.N = 512; a.K = 512;
    a.relu = 1; a.batch = 1;
    bgemm_launch<0>(stream, a);

    // 7. z and z^T + fused row softmax (key = sentence b^64) -> SP
    a = {}; a.A0 = Q; a.K0 = 512; a.lda0 = 512; a.bsA0 = bsQ;
    a.B = Q; a.ldb = 512; a.bsB = bsQ; a.bxor = 64;
    a.C = SP; a.ldc = 256; a.bsC = bsS; a.M = 256; a.N = 256; a.K = 512;
    a.batch = 128; a.smask = MASK; a.distW = nullptr; a.diag = 0; a.maskXor = 64;
    bgemm_launch<1>(stream, a);

    // 8. merged attend: ATT[b] = SP[b] @ V[b^64] (V pre-reordered in VTF)
    a = {}; a.A0 = SP; a.K0 = 256; a.lda0 = 256; a.bsA0 = bsS;
    a.B = VTF; a.ldb = 256; a.bsB = bsV; a.bxor = 0;
    a.C = ATT; a.ldc = 1024; a.bsC = bsC;
    a.M = 256; a.N = 1024; a.K = 256; a.batch = 128;
    bgemm_launch<0>(stream, a);

    // 9. compare MLP layer 1 (K = 2048 via concat)
    a = {}; a.A0 = CAT; a.K0 = 1024; a.lda0 = 1024;
    a.A1 = ATT; a.lda1 = 1024;
    a.B = WTc1; a.ldb = 2048; a.bias = bc1;
    a.C = Hb; a.ldc = 512; a.M = BL2; a.N = 512; a.K = 2048;
    a.relu = 1; a.batch = 1;
    bgemm_launch<0>(stream, a);

    // 10. compare MLP layer 2 + fused masked position-sum -> R32
    a = {}; a.A0 = Hb; a.K0 = 512; a.lda0 = 512; a.B = WTc2; a.ldb = 512;
    a.bias = bc2; a.M = BL2; a.N = 512; a.K = 512; a.relu = 1; a.batch = 1;
    a.rout = R32; a.rmask = MASK; a.C = Hb; // C unused in MODE 2
    bgemm_launch<2>(stream, a);

    // 11. aggregate MLP (fp32) + output
    mlp_par_kernel<<<dim3(8, BB), 256, 0, stream>>>(R32, Wg1, bg1, H64, 1024);
    mlp_par_kernel<<<dim3(8, BB), 256, 0, stream>>>(H64, Wg2, bg2, G, 512);
    out_kernel<<<48, 256, 0, stream>>>(G, Wo, out);
}

// Round 11
// 615.663 us; speedup vs baseline: 1.1938x; 1.0163x over previous
//
#include <hip/hip_runtime.h>
#include <math.h>

#define BB   64
#define LL   256
#define EE   512
#define DD   512
#define BL   (BB * LL)      // 16384
#define BL2  (2 * BL)       // 32768 (prem rows then hypo rows)
#define MAX_DIST 11

typedef __attribute__((ext_vector_type(8))) short bf16x8;
typedef __attribute__((ext_vector_type(8))) unsigned short u16x8;
typedef __attribute__((ext_vector_type(4))) float f32x4;

__device__ __forceinline__ float bf2f(unsigned short u) {
    union { unsigned int u; float f; } v; v.u = ((unsigned int)u) << 16; return v.f;
}
__device__ __forceinline__ unsigned short f2bf(float f) {
    union { float f; unsigned int u; } v; v.f = f;
    unsigned int r = v.u + 0x7FFF + ((v.u >> 16) & 1);   // RNE
    return (unsigned short)(r >> 16);
}

#define GLOAD16(g, l)                                                          \
    __builtin_amdgcn_global_load_lds(                                          \
        (const __attribute__((address_space(1))) void*)(g),                    \
        (__attribute__((address_space(3))) void*)(l), 16, 0, 0)

// ---------------------------------------------------------------------------
// bf16 MFMA GEMM, BK=64, tile 128x256, 4 waves (wave tile 64x128).
// MODE 0: C = act([A0|A1]*B^T + bias), bf16 out, coalesced LDS epilogue.
// MODE 1: fused row-softmax epilogue (N==256): dist-bias/diag/key-mask,
//         full-row softmax (shuffle + cross-wave LDS), bf16 probs out.
// MODE 2: masked row-reduce epilogue: relu(acc+bias)*mask[row] summed over
//         rows, atomicAdd into rout [64,1024]; no C write.
// SHARE (compile-time): A rows are contained in the staged B tile (requires
//   A==B buffer, N==256, col0==0) -> skip A staging, read A frags from Bs
//   at global row row0+r.  Used only for self-scores Q@Q^T.
// B batch index is (b ^ bxor).
// Grid (M/128, N/256, batch): A-slab sharers land on one XCD (L2 reuse).
// LDS: rows of 64 bf16 = 8 x 16B chunks, chunk g of row r at slot g^(r&7).
// ---------------------------------------------------------------------------
template <int MODE, bool SHARE = false>
__global__ __launch_bounds__(256, 2) void bgemm_kernel(
    const unsigned short* __restrict__ A0, int K0, int lda0, long long bsA0,
    const unsigned short* __restrict__ A1, int lda1, long long bsA1,
    const unsigned short* __restrict__ B, int ldb, long long bsB, int bxor,
    const float* __restrict__ bias,
    void* __restrict__ Cv, int ldc, long long bsC,
    int K, int relu,
    const float* __restrict__ smask, const float* __restrict__ distW,
    int diag, int maskXor,
    float* __restrict__ rout, const float* __restrict__ rmask)
{
    constexpr int BN = 256;
    constexpr int NI = 8;
    __shared__ unsigned short smem[(128 + BN) * 64];
    unsigned short* As = smem;
    unsigned short* Bs = smem + 128 * 64;

    const int tid  = threadIdx.x;
    const int wave = tid >> 6;
    const int lane = tid & 63;
    const int quad = lane >> 4;
    const int l15  = lane & 15;
    const int wm   = (wave >> 1) * 64;
    const int wn   = (wave & 1) * 128;
    const int row0 = blockIdx.x * 128;
    const int col0 = blockIdx.y * BN;
    const int b    = blockIdx.z;

    const unsigned short* A0b = A0 + (long long)b * bsA0;
    const unsigned short* A1b = A1 ? (A1 + (long long)b * bsA1) : nullptr;
    const unsigned short* Bb  = B + (long long)(b ^ bxor) * bsB;

    f32x4 acc[4][NI];
#pragma unroll
    for (int i = 0; i < 4; ++i)
#pragma unroll
        for (int j = 0; j < NI; ++j)
            acc[i][j] = (f32x4){0.f, 0.f, 0.f, 0.f};

    for (int kk = 0; kk < K; kk += 64) {
        if constexpr (!SHARE) {
            const unsigned short* Ap; int lda, kloc;
            if (kk < K0) { Ap = A0b; lda = lda0; kloc = kk; }
            else         { Ap = A1b; lda = lda1; kloc = kk - K0; }
#pragma unroll
            for (int it = 0; it < 4; ++it) {
                const int c   = it * 256 + tid;
                const int row = c >> 3;
                const int kch = (c & 7) ^ (row & 7);
                GLOAD16(Ap + (long long)(row0 + row) * lda + kloc + kch * 8,
                        (char*)As + c * 16);
            }
        }
#pragma unroll
        for (int it = 0; it < 8; ++it) {
            const int c   = it * 256 + tid;
            const int row = c >> 3;
            const int kch = (c & 7) ^ (row & 7);
            GLOAD16(Bb + (long long)(col0 + row) * ldb + kk + kch * 8,
                    (char*)Bs + c * 16);
        }
        __syncthreads();

#pragma unroll
        for (int s = 0; s < 2; ++s) {
            bf16x8 fa[4], fb[NI];
#pragma unroll
            for (int mi = 0; mi < 4; ++mi) {
                if constexpr (SHARE) {
                    const int r = row0 + wm + mi * 16 + l15;  // global row in Bs
                    const int slot = (s * 4 + quad) ^ (r & 7);
                    fa[mi] = *(const bf16x8*)&Bs[(r * 8 + slot) * 8];
                } else {
                    const int r = wm + mi * 16 + l15;
                    const int slot = (s * 4 + quad) ^ (r & 7);
                    fa[mi] = *(const bf16x8*)&As[(r * 8 + slot) * 8];
                }
            }
#pragma unroll
            for (int ni = 0; ni < NI; ++ni) {
                const int r = wn + ni * 16 + l15;
                const int slot = (s * 4 + quad) ^ (r & 7);
                fb[ni] = *(const bf16x8*)&Bs[(r * 8 + slot) * 8];
            }
#pragma unroll
            for (int mi = 0; mi < 4; ++mi)
#pragma unroll
                for (int ni = 0; ni < NI; ++ni)
                    acc[mi][ni] = __builtin_amdgcn_mfma_f32_16x16x32_bf16(
                        fa[mi], fb[ni], acc[mi][ni], 0, 0, 0);
        }
        __syncthreads();
    }

    if constexpr (MODE == 2) {
        float bv[NI];
#pragma unroll
        for (int ni = 0; ni < NI; ++ni)
            bv[ni] = bias[col0 + wn + ni * 16 + l15];
        float mrow[4][4];
#pragma unroll
        for (int mi = 0; mi < 4; ++mi)
#pragma unroll
            for (int r = 0; r < 4; ++r)
                mrow[mi][r] = rmask[row0 + wm + mi * 16 + quad * 4 + r];
        float t[NI];
#pragma unroll
        for (int ni = 0; ni < NI; ++ni) t[ni] = 0.f;
#pragma unroll
        for (int mi = 0; mi < 4; ++mi)
#pragma unroll
            for (int ni = 0; ni < NI; ++ni)
#pragma unroll
                for (int r = 0; r < 4; ++r) {
                    float x = fmaxf(acc[mi][ni][r] + bv[ni], 0.f);
                    t[ni] = fmaf(x, mrow[mi][r], t[ni]);
                }
#pragma unroll
        for (int ni = 0; ni < NI; ++ni) {
            t[ni] += __shfl_xor(t[ni], 16, 64);
            t[ni] += __shfl_xor(t[ni], 32, 64);
        }
        if (quad == 0) {
            const int sb = row0 >> 8;                       // sentence-batch
            const int base = (sb & 63) * 1024 + (sb >> 6) * 512;
#pragma unroll
            for (int ni = 0; ni < NI; ++ni)
                atomicAdd(rout + base + col0 + wn + ni * 16 + l15, t[ni]);
        }
        return;
    }

    float bv[NI];
    if constexpr (MODE == 0) {
#pragma unroll
        for (int ni = 0; ni < NI; ++ni)
            bv[ni] = bias ? bias[col0 + wn + ni * 16 + l15] : 0.f;
    } else {
#pragma unroll
        for (int ni = 0; ni < NI; ++ni) bv[ni] = 0.f;
    }

    if constexpr (MODE == 1) {
        __shared__ float red[4][64];
        const int kb = b ^ maskXor;
        float mk[NI];
#pragma unroll
        for (int ni = 0; ni < NI; ++ni)
            mk[ni] = smask[kb * 256 + wn + ni * 16 + l15];
        float rm[4][4];
#pragma unroll
        for (int mi = 0; mi < 4; ++mi)
#pragma unroll
            for (int r = 0; r < 4; ++r) rm[mi][r] = -INFINITY;
#pragma unroll
        for (int mi = 0; mi < 4; ++mi)
#pragma unroll
            for (int r = 0; r < 4; ++r) {
                const int q = row0 + wm + mi * 16 + quad * 4 + r;
#pragma unroll
                for (int ni = 0; ni < NI; ++ni) {
                    const int j = wn + ni * 16 + l15;
                    float s = acc[mi][ni][r];
                    if (distW) {
                        int d = j - q;
                        d = d > MAX_DIST ? MAX_DIST : (d < -MAX_DIST ? -MAX_DIST : d);
                        s += distW[d + MAX_DIST];
                    }
                    if (diag && j == q) s = -INFINITY;
                    if (mk[ni] == 0.f) s = -1e9f;
                    acc[mi][ni][r] = s;
                    rm[mi][r] = fmaxf(rm[mi][r], s);
                }
            }
#pragma unroll
        for (int mi = 0; mi < 4; ++mi)
#pragma unroll
            for (int r = 0; r < 4; ++r) {
                float v = rm[mi][r];
                v = fmaxf(v, __shfl_xor(v, 1, 64));
                v = fmaxf(v, __shfl_xor(v, 2, 64));
                v = fmaxf(v, __shfl_xor(v, 4, 64));
                v = fmaxf(v, __shfl_xor(v, 8, 64));
                rm[mi][r] = v;
            }
        if (l15 == 0) {
#pragma unroll
            for (int mi = 0; mi < 4; ++mi)
#pragma unroll
                for (int r = 0; r < 4; ++r)
                    red[wave][mi * 16 + quad * 4 + r] = rm[mi][r];
        }
        __syncthreads();
#pragma unroll
        for (int mi = 0; mi < 4; ++mi)
#pragma unroll
            for (int r = 0; r < 4; ++r)
                rm[mi][r] = fmaxf(rm[mi][r],
                                  red[wave ^ 1][mi * 16 + quad * 4 + r]);
        float rs[4][4];
#pragma unroll
        for (int mi = 0; mi < 4; ++mi)
#pragma unroll
            for (int r = 0; r < 4; ++r) rs[mi][r] = 0.f;
#pragma unroll
        for (int mi = 0; mi < 4; ++mi)
#pragma unroll
            for (int ni = 0; ni < NI; ++ni)
#pragma unroll
                for (int r = 0; r < 4; ++r) {
                    float e = __expf(acc[mi][ni][r] - rm[mi][r]);
                    acc[mi][ni][r] = e;
                    rs[mi][r] += e;
                }
#pragma unroll
        for (int mi = 0; mi < 4; ++mi)
#pragma unroll
            for (int r = 0; r < 4; ++r) {
                float v = rs[mi][r];
                v += __shfl_xor(v, 1, 64);
                v += __shfl_xor(v, 2, 64);
                v += __shfl_xor(v, 4, 64);
                v += __shfl_xor(v, 8, 64);
                rs[mi][r] = v;
            }
        __syncthreads();
        if (l15 == 0) {
#pragma unroll
            for (int mi = 0; mi < 4; ++mi)
#pragma unroll
                for (int r = 0; r < 4; ++r)
                    red[wave][mi * 16 + quad * 4 + r] = rs[mi][r];
        }
        __syncthreads();
#pragma unroll
        for (int mi = 0; mi < 4; ++mi)
#pragma unroll
            for (int r = 0; r < 4; ++r) {
                const float tot = rs[mi][r] +
                                  red[wave ^ 1][mi * 16 + quad * 4 + r];
                const float inv = 1.f / tot;
#pragma unroll
                for (int ni = 0; ni < NI; ++ni)
                    acc[mi][ni][r] *= inv;
            }
        __syncthreads();
    }

    // coalesced bf16 epilogue: 32-row slabs through LDS, 16B packed stores
    {
        float* Ls = (float*)smem;                 // [32][257] fp32
        constexpr int LSW = 257;
        unsigned short* Cb = (unsigned short*)Cv + (long long)b * bsC;
#pragma unroll
        for (int h = 0; h < 4; ++h) {
            if ((wave >> 1) == (h >> 1)) {
                const int mi0 = (h & 1) * 2;
#pragma unroll
                for (int mm = 0; mm < 2; ++mm) {
#pragma unroll
                    for (int ni = 0; ni < NI; ++ni) {
#pragma unroll
                        for (int r = 0; r < 4; ++r) {
                            float x = acc[mi0 + mm][ni][r] + bv[ni];
                            if (MODE == 0 && relu) x = fmaxf(x, 0.f);
                            Ls[(mm * 16 + quad * 4 + r) * LSW +
                               wn + ni * 16 + l15] = x;
                        }
                    }
                }
            }
            __syncthreads();
#pragma unroll
            for (int it = 0; it < 4; ++it) {
                const int c  = it * 256 + tid;
                const int lr = c >> 5;           // /32 chunks-per-row
                const int cc = (c & 31) * 8;
                const float* src = &Ls[lr * LSW + cc];
                u16x8 u;
#pragma unroll
                for (int j = 0; j < 8; ++j) u[j] = f2bf(src[j]);
                *(u16x8*)(Cb + (long long)(row0 + h * 32 + lr) * ldc +
                          col0 + cc) = u;
            }
            __syncthreads();
        }
    }
}

// ---------------------------------------------------------------------------
// All-6 weight convert+transpose: W fp32 [K,512] -> WT bf16 [512,K]
// ---------------------------------------------------------------------------
struct WC6 {
    const float* s[6];
    unsigned short* d[6];
    int K[6];
};
__global__ void wconv6_kernel(WC6 wc)
{
    const int z = blockIdx.z;
    const int K = wc.K[z];
    const int k0 = blockIdx.y * 32;
    if (k0 >= K) return;
    const float* src = wc.s[z];
    unsigned short* dst = wc.d[z];
    __shared__ float tile[32][33];
    const int n0 = blockIdx.x * 32;
#pragma unroll
    for (int i = 0; i < 4; ++i)
        tile[threadIdx.y + i * 8][threadIdx.x] =
            src[(long long)(k0 + threadIdx.y + i * 8) * 512 + n0 + threadIdx.x];
    __syncthreads();
#pragma unroll
    for (int i = 0; i < 4; ++i)
        dst[(long long)(n0 + threadIdx.y + i * 8) * K + k0 + threadIdx.x] =
            f2bf(tile[threadIdx.x][threadIdx.y + i * 8]);
}

// ---------------------------------------------------------------------------
// Vectorized per-sentence transpose: src batch (bz^bxor) rows [256][1024],
// cols [0,C) -> dst[bz][c][l].  64x64 tiles, 16B/lane both directions,
// LDS pitch-72 round trip.  grid (C/64, 256/64, 128), block 256.
// ---------------------------------------------------------------------------
__global__ __launch_bounds__(256) void btransv_kernel(
    const unsigned short* __restrict__ src0, int lds_,
    unsigned short* __restrict__ dst0, int C, int bxor)
{
    __shared__ unsigned short T[64 * 72];
    const int bz = blockIdx.z;
    const int bs = bz ^ bxor;
    const int c0 = blockIdx.x * 64;
    const int l0 = blockIdx.y * 64;
    const unsigned short* src = src0 + (long long)bs * 256 * lds_;
    unsigned short* dst = dst0 + (long long)bz * C * 256;
#pragma unroll
    for (int it = 0; it < 2; ++it) {
        const int idx = it * 256 + threadIdx.x;    // 0..511
        const int l   = idx >> 3;                  // 0..63
        const int ch  = idx & 7;
        u16x8 v = *(const u16x8*)(src + (long long)(l0 + l) * lds_ +
                                  c0 + ch * 8);
        *(u16x8*)&T[l * 72 + ch * 8] = v;
    }
    __syncthreads();
#pragma unroll
    for (int it = 0; it < 2; ++it) {
        const int idx = it * 256 + threadIdx.x;
        const int c   = idx >> 3;                  // 0..63
        const int ch2 = idx & 7;                   // l-chunk
        u16x8 u;
#pragma unroll
        for (int j = 0; j < 8; ++j)
            u[j] = T[(ch2 * 8 + j) * 72 + c];
        *(u16x8*)(dst + (long long)(c0 + c) * 256 + l0 + ch2 * 8) = u;
    }
}

// Embedding gather (both sentences) + mask + R32 zeroing
__global__ void embed_kernel(const int* __restrict__ prem_tok,
                             const int* __restrict__ hypo_tok,
                             const float* __restrict__ W,
                             unsigned short* __restrict__ cat,
                             float* __restrict__ mask,
                             float* __restrict__ R32)
{
    const int row = blockIdx.x;
    const int t   = threadIdx.x;
    const int tok = row < BL ? prem_tok[row] : hypo_tok[row - BL];
    if (t == 0) mask[row] = (tok != 0) ? 1.0f : 0.0f;
    if (row < 64) {
        float4 z = {0.f, 0.f, 0.f, 0.f};
        ((float4*)(R32 + row * 1024))[t]       = z;
        ((float4*)(R32 + row * 1024))[t + 128] = z;
    }
    float4 v = ((const float4*)(W + (long long)tok * EE))[t];
    ushort4 o;
    o.x = f2bf(v.x); o.y = f2bf(v.y); o.z = f2bf(v.z); o.w = f2bf(v.w);
    ((ushort4*)(cat + (long long)row * 1024))[t] = o;
}

// Parallel small fp32 MLP layer: grid (8, BB), block 256
__global__ __launch_bounds__(256) void mlp_par_kernel(
    const float* __restrict__ X, const float* __restrict__ W,
    const float* __restrict__ bias, float* __restrict__ Y, int Kin)
{
    __shared__ float red[4][64];
    const int b  = blockIdx.y;
    const int n  = blockIdx.x * 64 + (threadIdx.x & 63);
    const int ts = threadIdx.x >> 6;
    const int kc = Kin >> 2;
    const float* x = X + (long long)b * Kin + ts * kc;
    const float* w = W + (long long)(ts * kc) * 512 + n;
    float a0 = 0.f, a1 = 0.f;
#pragma unroll 8
    for (int k = 0; k < kc; k += 2) {
        a0 = fmaf(x[k],     w[(long long)k * 512],       a0);
        a1 = fmaf(x[k + 1], w[(long long)(k + 1) * 512], a1);
    }
    red[ts][threadIdx.x & 63] = a0 + a1;
    __syncthreads();
    if (ts == 0) {
        float v = red[0][threadIdx.x] + red[1][threadIdx.x] +
                  red[2][threadIdx.x] + red[3][threadIdx.x] + bias[n];
        Y[b * 512 + n] = fmaxf(v, 0.f);
    }
}

// Final output: one wave per (b,o).  grid 48 x 256 thr = 192 waves.
__global__ void out_kernel(const float* __restrict__ G,
                           const float* __restrict__ Wo,
                           float* __restrict__ out)
{
    const int wid  = blockIdx.x * 4 + (threadIdx.x >> 6);
    const int lane = threadIdx.x & 63;
    const int b = wid / 3, o = wid % 3;
    float acc = 0.f;
#pragma unroll
    for (int j = 0; j < 8; ++j) {
        int d = lane + j * 64;
        acc = fmaf(G[b * DD + d], Wo[d * 3 + o], acc);
    }
#pragma unroll
    for (int st = 32; st > 0; st >>= 1)
        acc += __shfl_down(acc, st, 64);
    if (lane == 0) out[wid] = acc;
}

// ---------------------------------------------------------------------------
// Host-side launcher
// ---------------------------------------------------------------------------
struct GemmArgs {
    const unsigned short *A0, *A1, *B;
    int K0, lda0, lda1, ldb;
    long long bsA0, bsA1, bsB;
    int bxor;
    const float* bias;
    void* C; int ldc; long long bsC;
    int M, N, K, relu, batch;
    const float* smask; const float* distW; int diag; int maskXor;
    float* rout; const float* rmask;
};

template <int MODE, bool SHARE = false>
static inline void bgemm_launch(hipStream_t stream, const GemmArgs& a)
{
    dim3 grid(a.M / 128, a.N / 256, a.batch);
    bgemm_kernel<MODE, SHARE><<<grid, 256, 0, stream>>>(
        a.A0, a.K0, a.lda0, a.bsA0, a.A1, a.lda1, a.bsA1,
        a.B, a.ldb, a.bsB, a.bxor, a.bias, a.C, a.ldc, a.bsC,
        a.K, a.relu, a.smask, a.distW, a.diag, a.maskXor, a.rout, a.rmask);
}

extern "C" void kernel_launch(void* const* d_in, const int* in_sizes, int n_in,
                              void* d_out, int out_size, void* d_ws, size_t ws_size,
                              hipStream_t stream)
{
    (void)in_sizes; (void)n_in; (void)out_size; (void)ws_size;

    const int*   prem_tok = (const int*)d_in[0];
    const int*   hypo_tok = (const int*)d_in[1];
    const float* embW = (const float*)d_in[2];
    const float* dW   = (const float*)d_in[3];
    const float* Ws1  = (const float*)d_in[4];
    const float* bs1  = (const float*)d_in[5];
    const float* Ws2  = (const float*)d_in[6];
    const float* bs2  = (const float*)d_in[7];
    const float* Wa1  = (const float*)d_in[8];
    const float* ba1  = (const float*)d_in[9];
    const float* Wa2  = (const float*)d_in[10];
    const float* ba2  = (const float*)d_in[11];
    const float* Wc1  = (const float*)d_in[12];
    const float* bc1  = (const float*)d_in[13];
    const float* Wc2  = (const float*)d_in[14];
    const float* bc2  = (const float*)d_in[15];
    const float* Wg1  = (const float*)d_in[16];
    const float* bg1  = (const float*)d_in[17];
    const float* Wg2  = (const float*)d_in[18];
    const float* bg2  = (const float*)d_in[19];
    const float* Wo   = (const float*)d_in[20];
    float* out = (float*)d_out;

    // ---- workspace carve-up (bytes) ----
    char* ws = (char*)d_ws;
    size_t off = 0;
    auto alloc = [&](size_t bytes) {
        char* p = ws + off; off += (bytes + 255) & ~(size_t)255; return p;
    };
    unsigned short* CAT  = (unsigned short*)alloc((size_t)BL2 * 1024 * 2);
    unsigned short* VTF  = (unsigned short*)alloc((size_t)128 * 1024 * 256 * 2);
    unsigned short* Hb   = (unsigned short*)alloc((size_t)BL2 * 512 * 2);
    unsigned short* Q    = (unsigned short*)alloc((size_t)BL2 * 512 * 2);
    unsigned short* ATT  = (unsigned short*)alloc((size_t)BL2 * 1024 * 2);
    unsigned short* SP   = (unsigned short*)alloc((size_t)128 * LL * LL * 2);
    float*          MASK = (float*)alloc((size_t)BL2 * 4);
    float*          R32  = (float*)alloc((size_t)BB * 1024 * 4);
    float*          H64  = (float*)alloc((size_t)BB * 512 * 4);
    float*          G    = (float*)alloc((size_t)BB * 512 * 4);
    unsigned short* WTs1 = (unsigned short*)alloc((size_t)512 * 512 * 2);
    unsigned short* WTs2 = (unsigned short*)alloc((size_t)512 * 512 * 2);
    unsigned short* WTa1 = (unsigned short*)alloc((size_t)1024 * 512 * 2);
    unsigned short* WTa2 = (unsigned short*)alloc((size_t)512 * 512 * 2);
    unsigned short* WTc1 = (unsigned short*)alloc((size_t)2048 * 512 * 2);
    unsigned short* WTc2 = (unsigned short*)alloc((size_t)512 * 512 * 2);

    const long long bsQ = (long long)LL * DD;       // 131072
    const long long bsS = (long long)LL * LL;       // 65536
    const long long bsC = (long long)LL * 1024;     // 262144
    const long long bsV = (long long)1024 * 256;    // VTF batch stride (full)

    dim3 tb(32, 8);

    // 0. weights -> [512, K] bf16
    WC6 wc;
    wc.s[0] = Ws1; wc.d[0] = WTs1; wc.K[0] = 512;
    wc.s[1] = Ws2; wc.d[1] = WTs2; wc.K[1] = 512;
    wc.s[2] = Wa1; wc.d[2] = WTa1; wc.K[2] = 1024;
    wc.s[3] = Wa2; wc.d[3] = WTa2; wc.K[3] = 512;
    wc.s[4] = Wc1; wc.d[4] = WTc1; wc.K[4] = 2048;
    wc.s[5] = Wc2; wc.d[5] = WTc2; wc.K[5] = 512;
    wconv6_kernel<<<dim3(16, 64, 6), tb, 0, stream>>>(wc);

    // 1. embeddings + masks + R32 zero
    embed_kernel<<<BL2, 128, 0, stream>>>(prem_tok, hypo_tok, embW, CAT,
                                          MASK, R32);

    GemmArgs a = {};

    // 2. self MLP (merged M=32768)
    a = {}; a.A0 = CAT; a.K0 = 512; a.lda0 = 1024; a.B = WTs1; a.ldb = 512;
    a.bias = bs1; a.C = Hb; a.ldc = 512; a.M = BL2; a.N = 512; a.K = 512;
    a.relu = 1; a.batch = 1;
    bgemm_launch<0>(stream, a);
    a = {}; a.A0 = Hb; a.K0 = 512; a.lda0 = 512; a.B = WTs2; a.ldb = 512;
    a.bias = bs2; a.C = Q; a.ldc = 512; a.M = BL2; a.N = 512; a.K = 512;
    a.relu = 1; a.batch = 1;
    bgemm_launch<0>(stream, a);

    // x^T per sentence (cols 0..511) -> VTF [128][512][256]
    btransv_kernel<<<dim3(8, 4, 128), 256, 0, stream>>>(CAT, 1024, VTF, 512, 0);

    // 3. self scores + fused softmax -> SP  (SHARE: A==B, skip A staging)
    a = {}; a.A0 = Q; a.K0 = 512; a.lda0 = 512; a.bsA0 = bsQ;
    a.B = Q; a.ldb = 512; a.bsB = bsQ; a.bxor = 0;
    a.C = SP; a.ldc = 256; a.bsC = bsS; a.M = 256; a.N = 256; a.K = 512;
    a.batch = 128; a.smask = MASK; a.distW = dW; a.diag = 1; a.maskXor = 0;
    bgemm_launch<1, true>(stream, a);

    // 4. ctx = att @ x -> CAT cols [512,1024)
    a = {}; a.A0 = SP; a.K0 = 256; a.lda0 = 256; a.bsA0 = bsS;
    a.B = VTF; a.ldb = 256; a.bsB = (long long)512 * 256;
    a.C = CAT + 512; a.ldc = 1024; a.bsC = bsC;
    a.M = 256; a.N = 512; a.K = 256; a.batch = 128;
    bgemm_launch<0>(stream, a);

    // 5. full V^T, cross-ordered (batch z holds sentence z^64)
    btransv_kernel<<<dim3(16, 4, 128), 256, 0, stream>>>(CAT, 1024, VTF,
                                                         1024, 64);

    // 6. inter projections (merged)
    a = {}; a.A0 = CAT; a.K0 = 1024; a.lda0 = 1024; a.B = WTa1; a.ldb = 1024;
    a.bias = ba1; a.C = Hb; a.ldc = 512; a.M = BL2; a.N = 512; a.K = 1024;
    a.relu = 1; a.batch = 1;
    bgemm_launch<0>(stream, a);
    a = {}; a.A0 = Hb; a.K0 = 512; a.lda0 = 512; a.B = WTa2; a.ldb = 512;
    a.bias = ba2; a.C = Q; a.ldc = 512; a.M = BL2; a.N = 512; a.K = 512;
    a.relu = 1; a.batch = 1;
    bgemm_launch<0>(stream, a);

    // 7. z and z^T + fused row softmax (key = sentence b^64) -> SP
    a = {}; a.A0 = Q; a.K0 = 512; a.lda0 = 512; a.bsA0 = bsQ;
    a.B = Q; a.ldb = 512; a.bsB = bsQ; a.bxor = 64;
    a.C = SP; a.ldc = 256; a.bsC = bsS; a.M = 256; a.N = 256; a.K = 512;
    a.batch = 128; a.smask = MASK; a.distW = nullptr; a.diag = 0; a.maskXor = 64;
    bgemm_launch<1>(stream, a);

    // 8. merged attend: ATT[b] = SP[b] @ V[b^64] (V pre-reordered in VTF)
    a = {}; a.A0 = SP; a.K0 = 256; a.lda0 = 256; a.bsA0 = bsS;
    a.B = VTF; a.ldb = 256; a.bsB = bsV; a.bxor = 0;
    a.C = ATT; a.ldc = 1024; a.bsC = bsC;
    a.M = 256; a.N = 1024; a.K = 256; a.batch = 128;
    bgemm_launch<0>(stream, a);

    // 9. compare MLP layer 1 (K = 2048 via concat)
    a = {}; a.A0 = CAT; a.K0 = 1024; a.lda0 = 1024;
    a.A1 = ATT; a.lda1 = 1024;
    a.B = WTc1; a.ldb = 2048; a.bias = bc1;
    a.C = Hb; a.ldc = 512; a.M = BL2; a.N = 512; a.K = 2048;
    a.relu = 1; a.batch = 1;
    bgemm_launch<0>(stream, a);

    // 10. compare MLP layer 2 + fused masked position-sum -> R32
    a = {}; a.A0 = Hb; a.K0 = 512; a.lda0 = 512; a.B = WTc2; a.ldb = 512;
    a.bias = bc2; a.M = BL2; a.N = 512; a.K = 512; a.relu = 1; a.batch = 1;
    a.rout = R32; a.rmask = MASK; a.C = Hb; // C unused in MODE 2
    bgemm_launch<2>(stream, a);

    // 11. aggregate MLP (fp32) + output
    mlp_par_kernel<<<dim3(8, BB), 256, 0, stream>>>(R32, Wg1, bg1, H64, 1024);
    mlp_par_kernel<<<dim3(8, BB), 256, 0, stream>>>(H64, Wg2, bg2, G, 512);
    out_kernel<<<48, 256, 0, stream>>>(G, Wo, out);
}